// Round 1
// baseline (17.392 us; speedup 1.0000x reference)
//
#include <hip/hip_runtime.h>

// State: [8192 rows][64 cols] complex, stored as separate re/im float planes.
// out layout: [2][8192][64] float32 (re plane then im plane).
#define PLANE (8192 * 64)

__device__ __forceinline__ void gate_coeffs(float theta, float& a, float& s) {
    // truncated exp(-i*theta/2 * X) series, CUTOFF=10:
    // a = 1 - t^2/2! + t^4/4! - t^6/6! + t^8/8! - t^10/10!
    // s = t - t^3/3! + t^5/5! - t^7/7! + t^9/9!
    float t = 0.5f * theta;
    float u = t * t;
    s = t * (1.f + u * (-1.f/6.f + u * (1.f/120.f + u * (-1.f/5040.f + u * (1.f/362880.f)))));
    a = 1.f + u * (-0.5f + u * (1.f/24.f + u * (-1.f/720.f + u * (1.f/40320.f + u * (-1.f/3628800.f)))));
}

// Kernel A: gates on row-bits 0..5 (angle[12]..angle[7]).
// Block = one 64-row group x one 32-col half. grid = 128*2 = 256 blocks.
__global__ __launch_bounds__(256) void rx_low(const float* __restrict__ xr,
                                              const float* __restrict__ xi,
                                              const float* __restrict__ angle,
                                              float* __restrict__ out) {
    __shared__ float lre[64 * 32];
    __shared__ float lim[64 * 32];
    const int tid = threadIdx.x;
    const int g   = blockIdx.x >> 1;   // 0..127 (rows 64g..64g+63)
    const int ch  = blockIdx.x & 1;    // col half

    const float4* xr4 = (const float4*)xr;
    const float4* xi4 = (const float4*)xi;
    float4* lre4 = (float4*)lre;
    float4* lim4 = (float4*)lim;

    #pragma unroll
    for (int k = 0; k < 2; ++k) {      // 512 float4 per array / 256 threads
        int j  = tid + 256 * k;
        int lr = j >> 3, c4 = j & 7;
        int ga = (g * 64 + lr) * 16 + ch * 8 + c4;   // global float4 index in [8192][16]
        lre4[j] = xr4[ga];
        lim4[j] = xi4[ga];
    }
    __syncthreads();

    #pragma unroll
    for (int b = 0; b < 6; ++b) {
        float a, s;
        gate_coeffs(angle[12 - b], a, s);
        #pragma unroll
        for (int pp = 0; pp < 4; ++pp) {   // 1024 pairs / 256 threads
            int p  = tid + 256 * pp;
            int c  = p & 31;
            int rp = p >> 5;               // 0..31
            int lo = ((rp >> b) << (b + 1)) | (rp & ((1 << b) - 1));
            int i0 = lo * 32 + c;
            int i1 = i0 + (32 << b);       // (lo | 1<<b)*32 + c
            float x0r = lre[i0], x0i = lim[i0];
            float x1r = lre[i1], x1i = lim[i1];
            lre[i0] = a * x0r + s * x1i;
            lim[i0] = a * x0i - s * x1r;
            lre[i1] = a * x1r + s * x0i;
            lim[i1] = a * x1i - s * x0r;
        }
        __syncthreads();
    }

    float4* or4 = (float4*)out;
    float4* oi4 = (float4*)(out + PLANE);
    #pragma unroll
    for (int k = 0; k < 2; ++k) {
        int j  = tid + 256 * k;
        int lr = j >> 3, c4 = j & 7;
        int ga = (g * 64 + lr) * 16 + ch * 8 + c4;
        or4[ga] = lre4[j];
        oi4[ga] = lim4[j];
    }
}

// Kernel B: gates on row-bits 6..12 (angle[6]..angle[0]).
// Group g = low 6 bits of row; rows r = g + 64h, h = 0..127.
// Block = one group x one 32-col half. grid = 64*2 = 128 blocks. In-place on out.
__global__ __launch_bounds__(256) void rx_high(const float* __restrict__ angle,
                                               float* __restrict__ out) {
    __shared__ float lre[128 * 32];
    __shared__ float lim[128 * 32];
    const int tid = threadIdx.x;
    const int g   = blockIdx.x >> 1;   // 0..63
    const int ch  = blockIdx.x & 1;

    float4* or4 = (float4*)out;
    float4* oi4 = (float4*)(out + PLANE);
    float4* lre4 = (float4*)lre;
    float4* lim4 = (float4*)lim;

    #pragma unroll
    for (int k = 0; k < 4; ++k) {      // 1024 float4 per array / 256 threads
        int j  = tid + 256 * k;
        int h  = j >> 3, c4 = j & 7;
        int ga = (g + 64 * h) * 16 + ch * 8 + c4;
        lre4[j] = or4[ga];
        lim4[j] = oi4[ga];
    }
    __syncthreads();

    #pragma unroll
    for (int q = 0; q < 7; ++q) {      // global bit b = 6+q -> angle[6-q]
        float a, s;
        gate_coeffs(angle[6 - q], a, s);
        #pragma unroll
        for (int pp = 0; pp < 8; ++pp) {   // 2048 pairs / 256 threads
            int p  = tid + 256 * pp;
            int c  = p & 31;
            int hp = p >> 5;               // 0..63
            int h0 = ((hp >> q) << (q + 1)) | (hp & ((1 << q) - 1));
            int i0 = h0 * 32 + c;
            int i1 = i0 + (32 << q);
            float x0r = lre[i0], x0i = lim[i0];
            float x1r = lre[i1], x1i = lim[i1];
            lre[i0] = a * x0r + s * x1i;
            lim[i0] = a * x0i - s * x1r;
            lre[i1] = a * x1r + s * x0i;
            lim[i1] = a * x1i - s * x0r;
        }
        __syncthreads();
    }

    #pragma unroll
    for (int k = 0; k < 4; ++k) {
        int j  = tid + 256 * k;
        int h  = j >> 3, c4 = j & 7;
        int ga = (g + 64 * h) * 16 + ch * 8 + c4;
        or4[ga] = lre4[j];
        oi4[ga] = lim4[j];
    }
}

extern "C" void kernel_launch(void* const* d_in, const int* in_sizes, int n_in,
                              void* d_out, int out_size, void* d_ws, size_t ws_size,
                              hipStream_t stream) {
    const float* xr    = (const float*)d_in[0];
    const float* xi    = (const float*)d_in[1];
    const float* angle = (const float*)d_in[2];
    float* out = (float*)d_out;

    rx_low<<<256, 256, 0, stream>>>(xr, xi, angle, out);
    rx_high<<<128, 256, 0, stream>>>(angle, out);
}

// Round 2
// 14.204 us; speedup vs baseline: 1.2245x; 1.2245x over previous
//
#include <hip/hip_runtime.h>

// State: 8192 rows x 64 cols complex. Input/output: separate re/im float planes.
// out layout: [2][8192][64] float32.
// Row index r = m (low 6 bits) + 64*h (high 7 bits).
// Gate on angle[i] acts on row-bit (12-i) (kron puts factor 0 at MSB).
// Kernel A handles bits 0..5 (within 64-row groups, h fixed).
// Kernel B handles bits 6..12 (across h, m fixed).
// Intermediate in d_ws, complex-interleaved + quarter-blocked + bit-rotated:
//   ws4[(q*8192 + m*128 + h)*8 + cp], float4 = (re,im)x2cols, q = col quarter,
//   cp = col-pair within quarter. B block (m,q) then reads 1024 contiguous float4.
#define PLANE (8192 * 64)

__device__ __forceinline__ void gate_coeffs(float theta, float& a, float& s) {
    // truncated series, CUTOFF=10: a ~ cos(theta/2) thru t^10, s ~ sin(theta/2) thru t^9
    float t = 0.5f * theta;
    float u = t * t;
    s = t * (1.f + u * (-1.f/6.f + u * (1.f/120.f + u * (-1.f/5040.f + u * (1.f/362880.f)))));
    a = 1.f + u * (-0.5f + u * (1.f/24.f + u * (-1.f/720.f + u * (1.f/40320.f + u * (-1.f/3628800.f)))));
}

// v = (reA, imA, reB, imB) for two columns of one row.
__device__ __forceinline__ void butterfly(float4& v0, float4& v1, float a, float s) {
    float4 n0, n1;
    n0.x = a * v0.x + s * v1.y;
    n0.y = a * v0.y - s * v1.x;
    n0.z = a * v0.z + s * v1.w;
    n0.w = a * v0.w - s * v1.z;
    n1.x = a * v1.x + s * v0.y;
    n1.y = a * v1.y - s * v0.x;
    n1.z = a * v1.z + s * v0.w;
    n1.w = a * v1.w - s * v0.z;
    v0 = n0; v1 = n1;
}

// Kernel A: bits 0..5 (angle[12]..angle[7]). Block = 64 rows (g = h, fixed) x 16 cols.
// grid = 128 * 4 = 512 blocks.
__global__ __launch_bounds__(256) void rx_low(const float* __restrict__ xr,
                                              const float* __restrict__ xi,
                                              const float* __restrict__ angle,
                                              float4* __restrict__ ws4) {
    __shared__ float4 l4[64 * 8];      // 8 KB: [local row 0..63][col-pair 0..7]
    const int tid = threadIdx.x;
    const int g   = blockIdx.x >> 2;   // 0..127 (high 7 bits of row)
    const int q   = blockIdx.x & 3;    // col quarter (16 cols)

    const float4* xr4 = (const float4*)xr;
    const float4* xi4 = (const float4*)xi;

    {   // load + interleave: 256 float4 per plane
        int lr = tid >> 2, c4 = tid & 3;
        int ga = (g * 64 + lr) * 16 + q * 4 + c4;
        float4 re = xr4[ga];
        float4 im = xi4[ga];
        l4[lr * 8 + c4 * 2]     = make_float4(re.x, im.x, re.y, im.y);
        l4[lr * 8 + c4 * 2 + 1] = make_float4(re.z, im.z, re.w, im.w);
    }
    __syncthreads();

    #pragma unroll
    for (int b = 0; b < 6; ++b) {
        float a, s;
        gate_coeffs(angle[12 - b], a, s);
        int cp = tid & 7, rp = tid >> 3;   // 32 row-pairs x 8 col-pairs = 256 = 1/thread
        int lo = ((rp >> b) << (b + 1)) | (rp & ((1 << b) - 1));
        int i0 = lo * 8 + cp;
        int i1 = i0 + (8 << b);
        float4 v0 = l4[i0], v1 = l4[i1];
        butterfly(v0, v1, a, s);
        l4[i0] = v0; l4[i1] = v1;
        __syncthreads();
    }

    #pragma unroll
    for (int k = 0; k < 2; ++k) {      // 512 float4 out, bit-rotated scatter (64-128B chunks)
        int j = tid + 256 * k;
        int m = j >> 3, cp = j & 7;
        ws4[(q * 8192 + m * 128 + g) * 8 + cp] = l4[j];
    }
}

// Kernel B: bits 6..12 (angle[6]..angle[0]). Block = 128 h-values (g = m, fixed) x 16 cols.
// grid = 64 * 4 = 256 blocks. Reads ws fully coalesced via global_load_lds.
__global__ __launch_bounds__(256) void rx_high(const float* __restrict__ angle,
                                               const float4* __restrict__ ws4,
                                               float* __restrict__ out) {
    __shared__ float4 l4[128 * 8];     // 16 KB: [h 0..127][col-pair 0..7]
    const int tid = threadIdx.x;
    const int g   = blockIdx.x >> 2;   // 0..63 (low 6 bits of row)
    const int q   = blockIdx.x & 3;

    const float4* src = ws4 + (size_t)(q * 8192 + g * 128) * 8;  // 1024 contiguous float4
    typedef const __attribute__((address_space(1))) unsigned int* g32;
    typedef __attribute__((address_space(3))) unsigned int* l32;
    #pragma unroll
    for (int k = 0; k < 4; ++k) {
        int j = tid + 256 * k;
        __builtin_amdgcn_global_load_lds((g32)(src + j), (l32)(l4 + j), 16, 0, 0);
    }
    asm volatile("s_waitcnt vmcnt(0)" ::: "memory");
    __syncthreads();

    #pragma unroll
    for (int qq = 0; qq < 7; ++qq) {   // global row-bit 6+qq -> angle[6-qq]
        float a, s;
        gate_coeffs(angle[6 - qq], a, s);
        #pragma unroll
        for (int pp = 0; pp < 2; ++pp) {  // 64 h-pairs x 8 col-pairs = 512 = 2/thread
            int p  = tid + 256 * pp;
            int cp = p & 7, hp = p >> 3;
            int h0 = ((hp >> qq) << (qq + 1)) | (hp & ((1 << qq) - 1));
            int i0 = h0 * 8 + cp;
            int i1 = i0 + (8 << qq);
            float4 v0 = l4[i0], v1 = l4[i1];
            butterfly(v0, v1, a, s);
            l4[i0] = v0; l4[i1] = v1;
        }
        __syncthreads();
    }

    float2* outre2 = (float2*)out;
    float2* outim2 = (float2*)(out + PLANE);
    #pragma unroll
    for (int k = 0; k < 4; ++k) {      // de-interleave, 64B-chunk scatter stores
        int j = tid + 256 * k;
        int h = j >> 3, cp = j & 7;
        float4 v = l4[j];
        int r  = g + 64 * h;
        int o2 = r * 32 + q * 8 + cp;  // float2 index within a plane
        outre2[o2] = make_float2(v.x, v.z);
        outim2[o2] = make_float2(v.y, v.w);
    }
}

extern "C" void kernel_launch(void* const* d_in, const int* in_sizes, int n_in,
                              void* d_out, int out_size, void* d_ws, size_t ws_size,
                              hipStream_t stream) {
    const float* xr    = (const float*)d_in[0];
    const float* xi    = (const float*)d_in[1];
    const float* angle = (const float*)d_in[2];
    float*  out = (float*)d_out;
    float4* ws4 = (float4*)d_ws;

    rx_low<<<512, 256, 0, stream>>>(xr, xi, angle, ws4);
    rx_high<<<256, 256, 0, stream>>>(angle, ws4, out);
}